// Round 1
// baseline (213.323 us; speedup 1.0000x reference)
//
#include <hip/hip_runtime.h>

typedef unsigned int u32;
typedef unsigned short u16;
typedef __attribute__((ext_vector_type(8))) short bf16x8;
typedef __attribute__((ext_vector_type(8))) u16 u16x8;
typedef __attribute__((ext_vector_type(4))) float f32x4;

#define AS1 __attribute__((address_space(1)))
#define AS3 __attribute__((address_space(3)))

__device__ __forceinline__ void gload_lds16(const void* g, void* l) {
  __builtin_amdgcn_global_load_lds((const AS1 u32*)g, (AS3 u32*)l, 16, 0, 0);
}

__device__ __forceinline__ u16 f2bf(float f) {
  union { float f; u32 u; } x; x.f = f;
  u32 u = x.u;
  return (u16)((u + 0x7fffu + ((u >> 16) & 1u)) >> 16);
}

// ---------------- convert fp32 -> bf16 (q,k,v,Wq,Wk,Wv,Wo packed contiguously) ---------
__global__ __launch_bounds__(256) void convert_all(
    const float* __restrict__ q, const float* __restrict__ k, const float* __restrict__ v,
    const float* __restrict__ wq, const float* __restrict__ wk,
    const float* __restrict__ wv, const float* __restrict__ wo,
    u16* __restrict__ dst)
{
  int b = blockIdx.x, t = threadIdx.x;
  const float* sp; size_t lb;
  if (b < 6144) {
    sp = (b < 2048) ? q : ((b < 4096) ? k : v);
    lb = (size_t)(b & 2047) * 2048;
  } else {
    int w = (b - 6144) >> 9;
    sp = (w == 0) ? wq : ((w == 1) ? wk : ((w == 2) ? wv : wo));
    lb = (size_t)((b - 6144) & 511) * 2048;
  }
  lb += (size_t)t * 8;
  f32x4 f0 = *(const f32x4*)(sp + lb);
  f32x4 f1 = *(const f32x4*)(sp + lb + 4);
  u16x8 o;
  o[0]=f2bf(f0[0]); o[1]=f2bf(f0[1]); o[2]=f2bf(f0[2]); o[3]=f2bf(f0[3]);
  o[4]=f2bf(f1[0]); o[5]=f2bf(f1[1]); o[6]=f2bf(f1[2]); o[7]=f2bf(f1[3]);
  *(u16x8*)(dst + (size_t)b*2048 + (size_t)t*8) = o;
}

// ---------------- GEMM: C[M,N] = A[M,K] * B[N,K]^T + bias, bf16 in, OUT_T out ----------
// BM=128 BN=64 BK=64, 256 threads (4 waves, 2x2), wave tile 64x32.
template<typename OUT_T>
__global__ __launch_bounds__(256) void gemm_nt(
    const u16* __restrict__ A, const u16* __restrict__ Bw,
    const float* __restrict__ bias, OUT_T* __restrict__ C,
    int M, int N, int K)
{
  __shared__ __align__(16) u16 As[128*64];
  __shared__ __align__(16) u16 Bs[64*64];
  const int t = threadIdx.x;
  const int wid = t >> 6, l = t & 63;
  const int l4 = l >> 4, l15 = l & 15;
  const int m0 = blockIdx.y * 128, n0 = blockIdx.x * 64;
  const int wr = wid >> 1, wc = wid & 1;
  const int arow = t >> 3, achk = t & 7;

  f32x4 acc[4][2] = {};

  for (int k0 = 0; k0 < K; k0 += 64) {
    __syncthreads();
#pragma unroll
    for (int i = 0; i < 4; ++i) {
      int row = i*32 + arow;
      gload_lds16(A + (size_t)(m0+row)*K + k0 + ((achk ^ (row&7)) << 3),
                  &As[i*2048 + wid*512]);
    }
#pragma unroll
    for (int i = 0; i < 2; ++i) {
      int row = i*32 + arow;
      gload_lds16(Bw + (size_t)(n0+row)*K + k0 + ((achk ^ (row&7)) << 3),
                  &Bs[i*2048 + wid*512]);
    }
    __syncthreads();
#pragma unroll
    for (int kh = 0; kh < 2; ++kh) {
      bf16x8 af[4], bf[2];
#pragma unroll
      for (int mf = 0; mf < 4; ++mf) {
        int row = wr*64 + mf*16 + l15;
        int ch = (kh*4 + l4) ^ (row & 7);
        af[mf] = *(const bf16x8*)&As[row*64 + ch*8];
      }
#pragma unroll
      for (int nf = 0; nf < 2; ++nf) {
        int row = wc*32 + nf*16 + l15;
        int ch = (kh*4 + l4) ^ (row & 7);
        bf[nf] = *(const bf16x8*)&Bs[row*64 + ch*8];
      }
#pragma unroll
      for (int mf = 0; mf < 4; ++mf)
#pragma unroll
        for (int nf = 0; nf < 2; ++nf)
          acc[mf][nf] = __builtin_amdgcn_mfma_f32_16x16x32_bf16(af[mf], bf[nf], acc[mf][nf], 0, 0, 0);
    }
  }
#pragma unroll
  for (int mf = 0; mf < 4; ++mf)
#pragma unroll
    for (int nf = 0; nf < 2; ++nf) {
      int row = m0 + wr*64 + mf*16 + l4*4;
      int col = n0 + wc*32 + nf*16 + l15;
      float bv = bias[col];
#pragma unroll
      for (int r = 0; r < 4; ++r) {
        float val = acc[mf][nf][r] + bv;
        if constexpr (sizeof(OUT_T) == 2) C[(size_t)(row+r)*N + col] = (OUT_T)f2bf(val);
        else                              C[(size_t)(row+r)*N + col] = val;
      }
    }
}

// ---------------- causal flash attention, DH=64, QBLK=128, KVBLK=64 --------------------
#define S_LEN 2048
#define DMODEL 1024

__global__ __launch_bounds__(256) void attn_fwd(
    const u16* __restrict__ Qp, const u16* __restrict__ Kp,
    const u16* __restrict__ Vp, u16* __restrict__ AO)
{
  // [0,8192): Q staging, then per-wave P regions (wave w: [w*2048, w*2048+2048))
  // [8192,12288): K tile [64][64] swizzled; [12288,16384): V^T tile [64][64] swizzled
  __shared__ __align__(16) u16 lds[16384];
  const int t = threadIdx.x;
  const int wid = t >> 6, l = t & 63;
  const int l4 = l >> 4, l15 = l & 15;
  const int q0 = blockIdx.x * 128;
  const int h = blockIdx.y, b = blockIdx.z;
  const size_t hoff = (size_t)b * S_LEN * DMODEL + (size_t)h * 64;
  const u16* Qg = Qp + hoff;
  const u16* Kg = Kp + hoff;
  const u16* Vg = Vp + hoff;
  const int arow = t >> 3, achk = t & 7;

  // stage Q tile [128][64] swizzled
#pragma unroll
  for (int i = 0; i < 4; ++i) {
    int row = i*32 + arow;
    gload_lds16(Qg + (size_t)(q0+row)*DMODEL + ((achk ^ (row&7)) << 3),
                &lds[i*2048 + wid*512]);
  }
  __syncthreads();
  bf16x8 qf[2][2];
#pragma unroll
  for (int mf = 0; mf < 2; ++mf)
#pragma unroll
    for (int kh = 0; kh < 2; ++kh) {
      int row = wid*32 + mf*16 + l15;
      int ch = (kh*4 + l4) ^ (row & 7);
      qf[mf][kh] = *(const bf16x8*)&lds[row*64 + ch*8];
    }

  float mi[2][4], li[2][4];
  f32x4 o[2][4] = {};
#pragma unroll
  for (int mf = 0; mf < 2; ++mf)
#pragma unroll
    for (int r = 0; r < 4; ++r) { mi[mf][r] = -INFINITY; li[mf][r] = 0.f; }

  const int qw0 = q0 + wid*32;
  const int nt = q0/64 + 2;

  for (int kt = 0; kt < nt; ++kt) {
    const int k0 = kt*64;
    __syncthreads();
#pragma unroll
    for (int i = 0; i < 2; ++i) {           // K tile, swizzled, via global_load_lds
      int row = i*32 + arow;
      gload_lds16(Kg + (size_t)(k0+row)*DMODEL + ((achk ^ (row&7)) << 3),
                  &lds[8192 + i*2048 + wid*512]);
    }
#pragma unroll
    for (int i = 0; i < 2; ++i) {           // V tile transposed via regs, two-level swizzle
      int vr = i*32 + arow;
      u16x8 vv = *(const u16x8*)(Vg + (size_t)(k0+vr)*DMODEL + achk*8);
#pragma unroll
      for (int j = 0; j < 8; ++j) {
        int d = achk*8 + j;
        int ch = (vr >> 3) ^ (d & 7) ^ ((d >> 3) & 7);
        lds[12288 + d*64 + ch*8 + (vr & 7)] = vv[j];
      }
    }
    __syncthreads();

    if (k0 <= qw0 + 31) {
      f32x4 s[2][4] = {};
#pragma unroll
      for (int kh = 0; kh < 2; ++kh) {
        bf16x8 kf[4];
#pragma unroll
        for (int nf = 0; nf < 4; ++nf) {
          int row = nf*16 + l15;
          int ch = (kh*4 + l4) ^ (row & 7);
          kf[nf] = *(const bf16x8*)&lds[8192 + row*64 + ch*8];
        }
#pragma unroll
        for (int mf = 0; mf < 2; ++mf)
#pragma unroll
          for (int nf = 0; nf < 4; ++nf)
            s[mf][nf] = __builtin_amdgcn_mfma_f32_16x16x32_bf16(qf[mf][kh], kf[nf], s[mf][nf], 0,0,0);
      }
      const bool needmask = (k0 + 63) > qw0;
      float corr[2][4];
#pragma unroll
      for (int mf = 0; mf < 2; ++mf)
#pragma unroll
        for (int r = 0; r < 4; ++r) {
          float mx = -INFINITY;
#pragma unroll
          for (int nf = 0; nf < 4; ++nf) {
            float vsc = s[mf][nf][r] * 0.125f;
            if (needmask) {
              int qq = qw0 + mf*16 + l4*4 + r;
              int kk2 = k0 + nf*16 + l15;
              if (kk2 > qq) vsc = -INFINITY;
            }
            s[mf][nf][r] = vsc;
            mx = fmaxf(mx, vsc);
          }
          mx = fmaxf(mx, __shfl_xor(mx, 1, 64));
          mx = fmaxf(mx, __shfl_xor(mx, 2, 64));
          mx = fmaxf(mx, __shfl_xor(mx, 4, 64));
          mx = fmaxf(mx, __shfl_xor(mx, 8, 64));
          float mn = fmaxf(mi[mf][r], mx);
          corr[mf][r] = __expf(mi[mf][r] - mn);
          float sum = 0.f;
#pragma unroll
          for (int nf = 0; nf < 4; ++nf) {
            float p = __expf(s[mf][nf][r] - mn);
            s[mf][nf][r] = p;
            sum += p;
          }
          sum += __shfl_xor(sum, 1, 64);
          sum += __shfl_xor(sum, 2, 64);
          sum += __shfl_xor(sum, 4, 64);
          sum += __shfl_xor(sum, 8, 64);
          li[mf][r] = li[mf][r]*corr[mf][r] + sum;
          mi[mf][r] = mn;
        }
#pragma unroll
      for (int mf = 0; mf < 2; ++mf)
#pragma unroll
        for (int df = 0; df < 4; ++df)
#pragma unroll
          for (int r = 0; r < 4; ++r) o[mf][df][r] *= corr[mf][r];
      // P -> LDS (wave-private, reuses Q region), swizzled
      const int pbase = wid*2048;
#pragma unroll
      for (int mf = 0; mf < 2; ++mf)
#pragma unroll
        for (int nf = 0; nf < 4; ++nf)
#pragma unroll
          for (int r = 0; r < 4; ++r) {
            int prow = mf*16 + l4*4 + r;
            int pcol = nf*16 + l15;
            lds[pbase + prow*64 + (((pcol>>3) ^ (prow&7))<<3) + (pcol&7)] = f2bf(s[mf][nf][r]);
          }
      asm volatile("s_waitcnt lgkmcnt(0)" ::: "memory");
      // PV
#pragma unroll
      for (int kh = 0; kh < 2; ++kh) {
        bf16x8 pf[2], vf[4];
#pragma unroll
        for (int mf = 0; mf < 2; ++mf) {
          int prow = mf*16 + l15;
          int ch = (kh*4 + l4) ^ (prow & 7);
          pf[mf] = *(const bf16x8*)&lds[pbase + prow*64 + ch*8];
        }
#pragma unroll
        for (int df = 0; df < 4; ++df) {
          int d = df*16 + l15;
          int ch = (kh*4 + l4) ^ (d & 7) ^ ((d >> 3) & 7);
          vf[df] = *(const bf16x8*)&lds[12288 + d*64 + ch*8];
        }
#pragma unroll
        for (int mf = 0; mf < 2; ++mf)
#pragma unroll
          for (int df = 0; df < 4; ++df)
            o[mf][df] = __builtin_amdgcn_mfma_f32_16x16x32_bf16(pf[mf], vf[df], o[mf][df], 0,0,0);
      }
    }
  }
#pragma unroll
  for (int mf = 0; mf < 2; ++mf)
#pragma unroll
    for (int df = 0; df < 4; ++df) {
      int row = qw0 + mf*16 + l4*4;
      int col = h*64 + df*16 + l15;
#pragma unroll
      for (int r = 0; r < 4; ++r) {
        float val = o[mf][df][r] / li[mf][r];
        AO[((size_t)b*S_LEN + row + r)*DMODEL + col] = f2bf(val);
      }
    }
}

// ---------------------------------------------------------------------------------------
extern "C" void kernel_launch(void* const* d_in, const int* in_sizes, int n_in,
                              void* d_out, int out_size, void* d_ws, size_t ws_size,
                              hipStream_t stream)
{
  const float* q  = (const float*)d_in[0];
  const float* k  = (const float*)d_in[1];
  const float* v  = (const float*)d_in[2];
  // d_in[3] = mask (causal tril; applied analytically)
  const float* Wq = (const float*)d_in[4];
  const float* bq = (const float*)d_in[5];
  const float* Wk = (const float*)d_in[6];
  const float* bk = (const float*)d_in[7];
  const float* Wv = (const float*)d_in[8];
  const float* bv = (const float*)d_in[9];
  const float* Wo = (const float*)d_in[10];
  const float* bo = (const float*)d_in[11];
  float* out = (float*)d_out;

  u16* ws  = (u16*)d_ws;
  u16* qb  = ws;                 // [4096,1024] bf16
  u16* Wqb = ws + 12582912;
  u16* Wkb = ws + 13631488;
  u16* Wvb = ws + 14680064;
  u16* Wob = ws + 15728640;
  u16* kb  = ws + 4194304;
  u16* vb  = ws + 8388608;
  u16* Qp  = ws + 16777216;
  u16* Kp  = ws + 20971520;
  u16* Vp  = ws + 25165824;
  u16* AO  = ws + 29360128;      // total 33554432 u16 = 64 MB

  convert_all<<<8192, 256, 0, stream>>>(q, k, v, Wq, Wk, Wv, Wo, qb);

  dim3 g1(16, 32);
  gemm_nt<u16><<<g1, 256, 0, stream>>>(qb, Wqb, bq, Qp, 4096, 1024, 1024);
  gemm_nt<u16><<<g1, 256, 0, stream>>>(kb, Wkb, bk, Kp, 4096, 1024, 1024);
  gemm_nt<u16><<<g1, 256, 0, stream>>>(vb, Wvb, bv, Vp, 4096, 1024, 1024);

  dim3 ga(16, 16, 2);
  attn_fwd<<<ga, 256, 0, stream>>>(Qp, Kp, Vp, AO);

  gemm_nt<float><<<g1, 256, 0, stream>>>(AO, Wob, bo, out, 4096, 1024, 1024);
}